// Round 4
// baseline (135.146 us; speedup 1.0000x reference)
//
#include <hip/hip_runtime.h>
#include <stdint.h>

// Gumbel-max sampler, single fused launch.
// grid = (8 segs, B rows) x 256 thr. Each thread: 4 clamped float4s per operand
// (8 loads in flight), straight-line. Block partial argmax -> ws key.
// Last block per row (atomic counter) reduces 8 keys -> token id.
//
// score'[v] = logits[v]*(1/(t*ln2)) - log2(max(-log2(u[v]), 1e-10/ln2))
// monotone transform of the reference score => identical argmax.
// Greedy rows (t<=1e-10): score'[v] = logits[v].

#define SEGS 8
#define T1 256

__device__ __forceinline__ uint32_t order_f32(float f) {
    uint32_t u = __float_as_uint(f);
    return (u & 0x80000000u) ? ~u : (u | 0x80000000u);
}

__device__ __forceinline__ void upd(float s, int idx, float& best, int& bidx) {
    if (s > best || (s == best && idx < bidx)) { best = s; bidx = idx; }
}

__global__ __launch_bounds__(T1) void sampler_fused_kernel(
        const float* __restrict__ logits,
        const float* __restrict__ temps,
        const float* __restrict__ u,
        unsigned long long* __restrict__ keys,   // [SEGS][B]
        unsigned int* __restrict__ cnt,          // [B], zeroed per launch
        int* __restrict__ out,
        int V, int B) {
    const int seg = blockIdx.x;
    const int row = blockIdx.y;
    const int nvec = V >> 2;
    const int chunk = (nvec + SEGS - 1) / SEGS;   // 4008 for V=128256
    const int lo = seg * chunk;
    const int hi = min(lo + chunk, nvec);
    const int tid = threadIdx.x;

    const float t = temps[row];
    const bool greedy = (t <= 1e-10f);
    const float invT = greedy ? 1.0f : (1.4426950408889634f / t);
    const float CLMP = 1.4426950408889634e-10f;   // 1e-10 / ln2

    const size_t rowoff = (size_t)row * (size_t)V;
    const float4* lrow = reinterpret_cast<const float4*>(logits + rowoff);
    const float4* urow = reinterpret_cast<const float4*>(u + rowoff);

    float best = -__builtin_inff();
    int bidx = 0x7fffffff;

    // chunk <= 4*T1, so one straight-line pass of 4 clamped indices covers it.
    // Duplicates from clamping are argmax-neutral (true index recorded).
    for (int k = lo + tid; k < hi; k += 4 * T1) {
        const int lim = hi - 1;
        int ia = k;
        int ib = k + T1     > lim ? lim : k + T1;
        int ic = k + 2 * T1 > lim ? lim : k + 2 * T1;
        int id = k + 3 * T1 > lim ? lim : k + 3 * T1;

        if (greedy) {
            float4 la = lrow[ia], lb = lrow[ib], lc = lrow[ic], ld = lrow[id];
            upd(la.x, 4*ia+0, best, bidx); upd(la.y, 4*ia+1, best, bidx);
            upd(la.z, 4*ia+2, best, bidx); upd(la.w, 4*ia+3, best, bidx);
            upd(lb.x, 4*ib+0, best, bidx); upd(lb.y, 4*ib+1, best, bidx);
            upd(lb.z, 4*ib+2, best, bidx); upd(lb.w, 4*ib+3, best, bidx);
            upd(lc.x, 4*ic+0, best, bidx); upd(lc.y, 4*ic+1, best, bidx);
            upd(lc.z, 4*ic+2, best, bidx); upd(lc.w, 4*ic+3, best, bidx);
            upd(ld.x, 4*id+0, best, bidx); upd(ld.y, 4*id+1, best, bidx);
            upd(ld.z, 4*id+2, best, bidx); upd(ld.w, 4*id+3, best, bidx);
        } else {
            float4 la = lrow[ia], lb = lrow[ib], lc = lrow[ic], ld = lrow[id];
            float4 ua = urow[ia], ub = urow[ib], uc = urow[ic], ud = urow[id];
            float s;
            s = la.x * invT - __log2f(fmaxf(-__log2f(ua.x), CLMP)); upd(s, 4*ia+0, best, bidx);
            s = la.y * invT - __log2f(fmaxf(-__log2f(ua.y), CLMP)); upd(s, 4*ia+1, best, bidx);
            s = la.z * invT - __log2f(fmaxf(-__log2f(ua.z), CLMP)); upd(s, 4*ia+2, best, bidx);
            s = la.w * invT - __log2f(fmaxf(-__log2f(ua.w), CLMP)); upd(s, 4*ia+3, best, bidx);
            s = lb.x * invT - __log2f(fmaxf(-__log2f(ub.x), CLMP)); upd(s, 4*ib+0, best, bidx);
            s = lb.y * invT - __log2f(fmaxf(-__log2f(ub.y), CLMP)); upd(s, 4*ib+1, best, bidx);
            s = lb.z * invT - __log2f(fmaxf(-__log2f(ub.z), CLMP)); upd(s, 4*ib+2, best, bidx);
            s = lb.w * invT - __log2f(fmaxf(-__log2f(ub.w), CLMP)); upd(s, 4*ib+3, best, bidx);
            s = lc.x * invT - __log2f(fmaxf(-__log2f(uc.x), CLMP)); upd(s, 4*ic+0, best, bidx);
            s = lc.y * invT - __log2f(fmaxf(-__log2f(uc.y), CLMP)); upd(s, 4*ic+1, best, bidx);
            s = lc.z * invT - __log2f(fmaxf(-__log2f(uc.z), CLMP)); upd(s, 4*ic+2, best, bidx);
            s = lc.w * invT - __log2f(fmaxf(-__log2f(uc.w), CLMP)); upd(s, 4*ic+3, best, bidx);
            s = ld.x * invT - __log2f(fmaxf(-__log2f(ud.x), CLMP)); upd(s, 4*id+0, best, bidx);
            s = ld.y * invT - __log2f(fmaxf(-__log2f(ud.y), CLMP)); upd(s, 4*id+1, best, bidx);
            s = ld.z * invT - __log2f(fmaxf(-__log2f(ud.z), CLMP)); upd(s, 4*id+2, best, bidx);
            s = ld.w * invT - __log2f(fmaxf(-__log2f(ud.w), CLMP)); upd(s, 4*id+3, best, bidx);
        }
    }

    unsigned long long key =
        ((unsigned long long)order_f32(best) << 32) | (unsigned long long)(~(uint32_t)bidx);

    #pragma unroll
    for (int off = 32; off > 0; off >>= 1) {
        unsigned long long other = __shfl_down(key, off, 64);
        if (other > key) key = other;
    }

    __shared__ unsigned long long smax;
    __shared__ unsigned int sold;
    if (tid == 0) smax = 0ull;
    __syncthreads();
    if ((tid & 63) == 0) atomicMax(&smax, key);
    __syncthreads();

    if (tid == 0) {
        keys[(size_t)seg * B + row] = smax;
        __threadfence();                                // publish key (device scope)
        sold = atomicAdd(&cnt[row], 1u);                // device-coherent
    }
    __syncthreads();

    if (sold == SEGS - 1) {                             // last block for this row
        if (tid == 0) {
            __threadfence();
            unsigned long long bestk = 0ull;
            #pragma unroll
            for (int s = 0; s < SEGS; ++s) {
                // atomic RMW read -> coherent across XCD L2s
                unsigned long long k = atomicOr(&keys[(size_t)s * B + row], 0ull);
                if (k > bestk) bestk = k;
            }
            out[row] = (int)(~(uint32_t)(bestk & 0xffffffffull));
        }
    }
}

extern "C" void kernel_launch(void* const* d_in, const int* in_sizes, int n_in,
                              void* d_out, int out_size, void* d_ws, size_t ws_size,
                              hipStream_t stream) {
    const float* logits = (const float*)d_in[0];
    const float* temps  = (const float*)d_in[1];
    const float* u      = (const float*)d_in[2];
    int* out = (int*)d_out;

    const int B = in_sizes[1];
    const int V = in_sizes[0] / B;

    unsigned long long* keys = (unsigned long long*)d_ws;
    unsigned int* cnt = (unsigned int*)((char*)d_ws + (size_t)SEGS * B * sizeof(unsigned long long));

    hipMemsetAsync(cnt, 0, (size_t)B * sizeof(unsigned int), stream);

    dim3 grid(SEGS, B);
    sampler_fused_kernel<<<grid, T1, 0, stream>>>(logits, temps, u, keys, cnt, out, V, B);
}

// Round 5
// 45.550 us; speedup vs baseline: 2.9670x; 2.9670x over previous
//
#include <hip/hip_runtime.h>
#include <stdint.h>

// Gumbel-max sampler, single fused launch, FENCE-FREE finisher.
// grid = (8 segs, B rows) x 512 thr (R2's proven geometry).
// Each block: partial argmax over V/8 elems -> 64-bit key ->
//   global atomicMax(rowkey[row]) ; s_waitcnt vmcnt(0) ; atomicAdd(cnt[row]).
// 8th arriver reads final max via atomic RMW and writes the token.
// NO __threadfence (R4 lesson: buffer_wbl2/inv per block destroys stream BW).
//
// score'[v] = logits[v]*(1/(t*ln2)) - log2(max(-log2(u[v]), 1e-10/ln2))
// monotone transform of the reference score => identical argmax.
// Greedy rows (t<=1e-10): score'[v] = logits[v].

#define SEGS 8
#define T1 512

__device__ __forceinline__ uint32_t order_f32(float f) {
    uint32_t u = __float_as_uint(f);
    return (u & 0x80000000u) ? ~u : (u | 0x80000000u);
}

__device__ __forceinline__ void upd(float s, int idx, float& best, int& bidx) {
    if (s > best || (s == best && idx < bidx)) { best = s; bidx = idx; }
}

__global__ __launch_bounds__(T1) void sampler_fused_kernel(
        const float* __restrict__ logits,
        const float* __restrict__ temps,
        const float* __restrict__ u,
        unsigned long long* __restrict__ rowkey,   // [B], zeroed per launch
        unsigned int* __restrict__ cnt,            // [B], zeroed per launch
        int* __restrict__ out,
        int V, int B) {
    const int seg = blockIdx.x;
    const int row = blockIdx.y;
    const int chunk = V / SEGS;        // 16032 floats
    const int nvec = chunk >> 2;       // 4008 float4
    const int tid = threadIdx.x;

    const float t = temps[row];
    const bool greedy = (t <= 1e-10f);
    const float invT = greedy ? 1.0f : (1.4426950408889634f / t);
    const float CLMP = 1.4426950408889634e-10f;   // 1e-10 / ln2

    const size_t segoff = (size_t)row * (size_t)V + (size_t)seg * chunk;
    const float4* lseg = reinterpret_cast<const float4*>(logits + segoff);
    const float4* useg = reinterpret_cast<const float4*>(u + segoff);
    const int idx0 = seg * chunk;

    float best = -__builtin_inff();
    int bidx = 0x7fffffff;

    if (greedy) {
        for (int i = tid; i < nvec; i += T1) {
            float4 lg = lseg[i];
            const int base = idx0 + (i << 2);
            upd(lg.x, base + 0, best, bidx);
            upd(lg.y, base + 1, best, bidx);
            upd(lg.z, base + 2, best, bidx);
            upd(lg.w, base + 3, best, bidx);
        }
    } else {
        for (int i = tid; i < nvec; i += T1) {
            float4 lg = lseg[i];
            float4 uv = useg[i];
            const int base = idx0 + (i << 2);
            float s0 = lg.x * invT - __log2f(fmaxf(-__log2f(uv.x), CLMP));
            float s1 = lg.y * invT - __log2f(fmaxf(-__log2f(uv.y), CLMP));
            float s2 = lg.z * invT - __log2f(fmaxf(-__log2f(uv.z), CLMP));
            float s3 = lg.w * invT - __log2f(fmaxf(-__log2f(uv.w), CLMP));
            upd(s0, base + 0, best, bidx);
            upd(s1, base + 1, best, bidx);
            upd(s2, base + 2, best, bidx);
            upd(s3, base + 3, best, bidx);
        }
    }

    // pack: high 32 = ordered score, low 32 = ~idx (max => first-index tie-break)
    unsigned long long key =
        ((unsigned long long)order_f32(best) << 32) | (unsigned long long)(~(uint32_t)bidx);

    #pragma unroll
    for (int off = 32; off > 0; off >>= 1) {
        unsigned long long other = __shfl_down(key, off, 64);
        if (other > key) key = other;
    }

    __shared__ unsigned long long smax;
    if (tid == 0) smax = 0ull;
    __syncthreads();
    if ((tid & 63) == 0) atomicMax(&smax, key);
    __syncthreads();

    if (tid == 0) {
        // publish partial via device-coherent atomic (bypasses L1, no fence)
        atomicMax(&rowkey[row], smax);
        // ensure OUR atomic committed before signalling arrival (waits on this
        // wave's vmem only — no cache writeback/invalidate)
        asm volatile("s_waitcnt vmcnt(0)" ::: "memory");
        unsigned int old = atomicAdd(&cnt[row], 1u);
        if (old == SEGS - 1) {
            // all 8 partials committed (each preceded its arrival signal);
            // read final max coherently via RMW
            unsigned long long final_ = atomicMax(&rowkey[row], 0ull);
            out[row] = (int)(~(uint32_t)(final_ & 0xffffffffull));
        }
    }
}

extern "C" void kernel_launch(void* const* d_in, const int* in_sizes, int n_in,
                              void* d_out, int out_size, void* d_ws, size_t ws_size,
                              hipStream_t stream) {
    const float* logits = (const float*)d_in[0];
    const float* temps  = (const float*)d_in[1];
    const float* u      = (const float*)d_in[2];
    int* out = (int*)d_out;

    const int B = in_sizes[1];
    const int V = in_sizes[0] / B;

    unsigned long long* rowkey = (unsigned long long*)d_ws;
    unsigned int* cnt = (unsigned int*)((char*)d_ws + (size_t)B * sizeof(unsigned long long));

    // zero rowkey[B] + cnt[B] in one contiguous memset (12 B/row)
    hipMemsetAsync(d_ws, 0, (size_t)B * (sizeof(unsigned long long) + sizeof(unsigned int)), stream);

    dim3 grid(SEGS, B);
    sampler_fused_kernel<<<grid, T1, 0, stream>>>(logits, temps, u, rowkey, cnt, out, V, B);
}

// Round 6
// 39.911 us; speedup vs baseline: 3.3862x; 1.1413x over previous
//
#include <hip/hip_runtime.h>
#include <stdint.h>

// Gumbel-max sampler — R2 structure (measured best: 39.7 us), coalesced partials.
// Phase 1: 8 blocks/row x 512 thr, partial argmax over V/8 elems -> ws[seg*B+row].
// Phase 2: 1 block x B thr reduces 8 keys/row -> token id (coalesced reads).
//
// score'[v] = logits[v]*(1/(t*ln2)) - log2(max(-log2(u[v]), 1e-10/ln2))
// monotone transform of the reference score => identical argmax.
// Greedy rows (t<=1e-10): score'[v] = logits[v].

#define SEGS 8
#define T1 512

__device__ __forceinline__ uint32_t order_f32(float f) {
    uint32_t u = __float_as_uint(f);
    return (u & 0x80000000u) ? ~u : (u | 0x80000000u);
}

__device__ __forceinline__ void upd(float s, int idx, float& best, int& bidx) {
    if (s > best || (s == best && idx < bidx)) { best = s; bidx = idx; }
}

__global__ __launch_bounds__(T1) void sampler_part_kernel(
        const float* __restrict__ logits,
        const float* __restrict__ temps,
        const float* __restrict__ u,
        unsigned long long* __restrict__ ws,   // [SEGS][B]
        int V, int B) {
    const int seg = blockIdx.x;
    const int row = blockIdx.y;
    const int chunk = V / SEGS;        // 16032 floats
    const int nvec = chunk >> 2;       // 4008 float4
    const int tid = threadIdx.x;

    const float t = temps[row];
    const bool greedy = (t <= 1e-10f);
    const float invT = greedy ? 1.0f : (1.4426950408889634f / t);
    const float CLMP = 1.4426950408889634e-10f;   // 1e-10 / ln2

    const size_t segoff = (size_t)row * (size_t)V + (size_t)seg * chunk;
    const float4* lseg = reinterpret_cast<const float4*>(logits + segoff);
    const float4* useg = reinterpret_cast<const float4*>(u + segoff);
    const int idx0 = seg * chunk;

    float best = -__builtin_inff();
    int bidx = 0x7fffffff;

    if (greedy) {
        for (int i = tid; i < nvec; i += T1) {
            float4 lg = lseg[i];
            const int base = idx0 + (i << 2);
            upd(lg.x, base + 0, best, bidx);
            upd(lg.y, base + 1, best, bidx);
            upd(lg.z, base + 2, best, bidx);
            upd(lg.w, base + 3, best, bidx);
        }
    } else {
        for (int i = tid; i < nvec; i += T1) {
            float4 lg = lseg[i];
            float4 uv = useg[i];
            const int base = idx0 + (i << 2);
            float s0 = lg.x * invT - __log2f(fmaxf(-__log2f(uv.x), CLMP));
            float s1 = lg.y * invT - __log2f(fmaxf(-__log2f(uv.y), CLMP));
            float s2 = lg.z * invT - __log2f(fmaxf(-__log2f(uv.z), CLMP));
            float s3 = lg.w * invT - __log2f(fmaxf(-__log2f(uv.w), CLMP));
            upd(s0, base + 0, best, bidx);
            upd(s1, base + 1, best, bidx);
            upd(s2, base + 2, best, bidx);
            upd(s3, base + 3, best, bidx);
        }
    }

    // pack: high 32 = ordered score, low 32 = ~idx (max => first-index tie-break)
    unsigned long long key =
        ((unsigned long long)order_f32(best) << 32) | (unsigned long long)(~(uint32_t)bidx);

    #pragma unroll
    for (int off = 32; off > 0; off >>= 1) {
        unsigned long long other = __shfl_down(key, off, 64);
        if (other > key) key = other;
    }

    __shared__ unsigned long long smax;
    if (tid == 0) smax = 0ull;
    __syncthreads();
    if ((tid & 63) == 0) atomicMax(&smax, key);
    __syncthreads();
    if (tid == 0) ws[(size_t)seg * B + row] = smax;
}

__global__ __launch_bounds__(256) void sampler_reduce_kernel(
        const unsigned long long* __restrict__ ws,
        int* __restrict__ out, int B) {
    const int row = threadIdx.x;   // B threads, one block; reads coalesced
    unsigned long long best = 0ull;
    #pragma unroll
    for (int s = 0; s < SEGS; ++s) {
        unsigned long long k = ws[(size_t)s * B + row];
        if (k > best) best = k;
    }
    out[row] = (int)(~(uint32_t)(best & 0xffffffffull));
}

extern "C" void kernel_launch(void* const* d_in, const int* in_sizes, int n_in,
                              void* d_out, int out_size, void* d_ws, size_t ws_size,
                              hipStream_t stream) {
    const float* logits = (const float*)d_in[0];
    const float* temps  = (const float*)d_in[1];
    const float* u      = (const float*)d_in[2];
    int* out = (int*)d_out;
    unsigned long long* ws = (unsigned long long*)d_ws;

    const int B = in_sizes[1];
    const int V = in_sizes[0] / B;

    dim3 grid(SEGS, B);
    sampler_part_kernel<<<grid, T1, 0, stream>>>(logits, temps, u, ws, V, B);
    sampler_reduce_kernel<<<1, B, 0, stream>>>(ws, out, B);
}